// Round 6
// baseline (371.466 us; speedup 1.0000x reference)
//
#include <hip/hip_runtime.h>

#define BATCH 8192
#define DIM   512
// 64 straddle + 960 full above-diag + 128 quarter tiles (last 32 parents split 4-way in j)
#define NTILE 1152
#define NBLK  512          // exactly co-resident: 2 blocks/CU x 256 CU

typedef __attribute__((ext_vector_type(4))) float  f32x4;
typedef __attribute__((ext_vector_type(8))) __bf16 bf16x8;

__device__ __forceinline__ unsigned short f2bf(float x) {
  unsigned u = __float_as_uint(x);
  u = (u + 0x7FFFu + ((u >> 16) & 1u)) >> 16;   // RNE
  return (unsigned short)u;
}

__device__ __forceinline__ void load_lds16(const void* g, void* l) {
  __builtin_amdgcn_global_load_lds(
      (__attribute__((address_space(1))) void*)(g),
      (__attribute__((address_space(3))) void*)(l), 16, 0, 0);
}

// monotone float <-> uint encoding (order-preserving); sentinels 0x00000000 / 0xFFFFFFFF
__device__ __forceinline__ unsigned enc(float f) {
  unsigned u = __float_as_uint(f);
  return u ^ (unsigned)(((int)u >> 31) | 0x80000000);
}
__device__ __forceinline__ float dec(unsigned k) {
  unsigned u = (k & 0x80000000u) ? (k ^ 0x80000000u) : ~k;
  return __uint_as_float(u);
}

// ---------------- K-loop for one 128 x (NI*32) tile (R3-verbatim + setprio) -------
// NI=8,WNS=128: full 128x256 tile.  NI=2,WNS=32: 128x64 quarter.
template<int NI>
__device__ __forceinline__ void gemm_tile(
    const unsigned short* __restrict__ Xb, int i0, int jw,
    unsigned short* Asm, unsigned short* Bsm,
    int wave, int wm, int wn, int quad, int lc, int rc, int gcol,
    f32x4 (&acc)[4][8]) {
  for (int k0 = 0; k0 < DIM; k0 += 64) {
    #pragma unroll
    for (int tt = 0; tt < 4; tt++) {
      int c = wave * 4 + tt;
      int row = c * 8 + rc;
      load_lds16(Xb + (size_t)(i0 + row) * DIM + k0 + gcol, &Asm[c * 512]);
    }
    #pragma unroll
    for (int tt = 0; tt < NI; tt++) {          // NI loads/thread covers NI*32 B-rows
      int c = wave * NI + tt;
      int row = c * 8 + rc;
      load_lds16(Xb + (size_t)(jw + row) * DIM + k0 + gcol, &Bsm[c * 512]);
    }
    __syncthreads();
    #pragma unroll
    for (int kk = 0; kk < 64; kk += 32) {
      int kc = kk >> 3;
      int asel = ((kc + quad) ^ (lc & 7)) * 8;
      bf16x8 af[4], bfr[NI];
      #pragma unroll
      for (int mi = 0; mi < 4; mi++)
        af[mi] = *(const bf16x8*)&Asm[(wm * 64 + mi * 16 + lc) * 64 + asel];
      #pragma unroll
      for (int ni = 0; ni < NI; ni++)
        bfr[ni] = *(const bf16x8*)&Bsm[(wn * (NI * 16) + ni * 16 + lc) * 64 + asel];
      __builtin_amdgcn_s_setprio(1);           // T5: favor MFMA wave vs other block's staging
      #pragma unroll
      for (int mi = 0; mi < 4; mi++)
        #pragma unroll
        for (int ni = 0; ni < NI; ni++)
          acc[mi][ni] = __builtin_amdgcn_mfma_f32_16x16x32_bf16(
              af[mi], bfr[ni], acc[mi][ni], 0, 0, 0);
      __builtin_amdgcn_s_setprio(0);
    }
    __syncthreads();
  }
}

// Epilogue: i-mining always; j-mining (transposed) unless STRAD (diag straddle).
template<bool STRAD, int NI, int WNS>
__device__ __forceinline__ void epilogue(
    const f32x4 (&acc)[4][8], const float* __restrict__ sq,
    const int* __restrict__ labels,
    int i0, int jwin, int wm, int wn, int quad, int lc,
    unsigned (*ibuf)[128][2], unsigned (*jbuf)[256][2]) {
  float sqj_r[NI]; int labj_r[NI];
  #pragma unroll
  for (int ni = 0; ni < NI; ni++) {
    int j = jwin + wn * WNS + ni * 16 + lc;
    sqj_r[ni] = sq[j]; labj_r[ni] = labels[j];
  }
  float rpos[16], rneg[16];
  float jp[NI], jn[NI];
  #pragma unroll
  for (int x = 0; x < NI; x++) { jp[x] = -3e38f; jn[x] = 3e38f; }
  #pragma unroll
  for (int mi = 0; mi < 4; mi++) {
    #pragma unroll
    for (int r = 0; r < 4; r++) {
      int ig = i0 + wm * 64 + mi * 16 + quad * 4 + r;
      int li = labels[ig];
      float si = sq[ig];
      float rp = -3e38f, rn = 3e38f;
      #pragma unroll
      for (int ni = 0; ni < NI; ni++) {
        float a = acc[mi][ni][r];
        float v = fmaf(-2.f, a, sqj_r[ni]);        // sq_j - 2dot (sq_i added at end)
        bool same = (li == labj_r[ni]);
        bool posok = same;
        if (STRAD) posok = same && ((jwin + wn * WNS + ni * 16 + lc) != ig);
        rp = fmaxf(rp, posok ? v : -3e38f);
        rn = fminf(rn, same ? 3e38f : v);
        if (!STRAD) {                              // j-mining: sq_i - 2dot per column
          float v2 = fmaf(-2.f, a, si);
          jp[ni] = fmaxf(jp[ni], same ? v2 : -3e38f);
          jn[ni] = fminf(jn[ni], same ? 3e38f : v2);
        }
      }
      rpos[mi * 4 + r] = rp; rneg[mi * 4 + r] = rn;
    }
  }
  #pragma unroll
  for (int m = 1; m <= 8; m <<= 1)
    #pragma unroll
    for (int x = 0; x < 16; x++) {
      rpos[x] = fmaxf(rpos[x], __shfl_xor(rpos[x], m));
      rneg[x] = fminf(rneg[x], __shfl_xor(rneg[x], m));
    }
  if (lc == 0) {
    #pragma unroll
    for (int mi = 0; mi < 4; mi++)
      #pragma unroll
      for (int r = 0; r < 4; r++) {
        int row = wm * 64 + mi * 16 + quad * 4 + r;
        ibuf[wn][row][0] = enc(rpos[mi * 4 + r]);
        ibuf[wn][row][1] = enc(rneg[mi * 4 + r]);
      }
  }
  if (!STRAD) {
    #pragma unroll
    for (int m = 16; m <= 32; m <<= 1)
      #pragma unroll
      for (int x = 0; x < NI; x++) {
        jp[x] = fmaxf(jp[x], __shfl_xor(jp[x], m));
        jn[x] = fminf(jn[x], __shfl_xor(jn[x], m));
      }
    if (quad == 0) {
      #pragma unroll
      for (int ni = 0; ni < NI; ni++) {
        int col = wn * WNS + ni * 16 + lc;
        jbuf[wm][col][0] = enc(jp[ni]);
        jbuf[wm][col][1] = enc(jn[ni]);
      }
    }
  }
}

// ---------------- fused persistent kernel: prep | gridsync | tiles | gridsync | final -----
// R5 post-mortem: both hand-pipelines (R4/R5) lose to the compiler's 2-barrier
// schedule at 2 blocks/CU — keep R3's K-loop verbatim. The remaining ~73us of the
// e2e budget is OUTSIDE the main loop: 3 launches + a 32-block latency-bound final
// kernel. Fix: one persistent kernel. grid=512 with launch_bounds(256,2) is exactly
// co-resident (LDS 48.5KB -> 3 fit; regs bounded; waves 8/CU), so two ONE-SHOT grid
// syncs are deadlock-free. Cross-XCD visibility: plain stores + __threadfence
// (agent-scope wb/inv) + device-scope atomic counter — the documented pattern.
// Sentinels/ctrl move to hipMemsetAsync (graph-legal). Final phase now runs at 512
// blocks (16 rows each, coalesced slot reads) instead of 32. ctrl: [0]sum [1]cnt
// [2]ticket [3]queue [4]prep-sync [5]exit-sync.
__global__ __launch_bounds__(256, 2) void triplet_fused(
    const float* __restrict__ X, const int* __restrict__ labels,
    unsigned short* __restrict__ Xb, float* __restrict__ sq,
    unsigned* __restrict__ ctrl,
    unsigned* __restrict__ pos_i, unsigned* __restrict__ neg_i,
    unsigned* __restrict__ pos_j, unsigned* __restrict__ neg_j,
    float* __restrict__ out) {
  __shared__ __align__(16) unsigned short Asm[128 * 64];  // 16 KB
  __shared__ __align__(16) unsigned short Bsm[256 * 64];  // 32 KB
  __shared__ int tshare;

  // overlays on Asm (dead between K-loop end and next staging / after tile loop):
  unsigned (*ibuf)[128][2] = reinterpret_cast<unsigned (*)[128][2]>(&Asm[0]);     // 2 KB
  unsigned (*jbuf)[256][2] = reinterpret_cast<unsigned (*)[256][2]>(&Asm[1024]);  // 4 KB
  unsigned (*fbuf)[16][2]  = reinterpret_cast<unsigned (*)[16][2]>(&Asm[3072]);   // 512 B

  int tid = threadIdx.x;
  int wave = tid >> 6, lane = tid & 63;
  int wm = wave >> 1, wn = wave & 1;
  int quad = lane >> 4, lc = lane & 15;
  int rc = lane >> 3;
  int gcol = ((lane & 7) ^ rc) * 8;          // XOR swizzle (verified: 0 conflicts)

  // ---------------- phase 1: prep (fp32->bf16 + row norms), 16 rows/block ----------------
  #pragma unroll
  for (int it = 0; it < 4; it++) {
    int row = blockIdx.x * 16 + it * 4 + wave;
    const float4* xr = (const float4*)(X + (size_t)row * DIM);
    float4 a = xr[lane * 2];
    float4 b = xr[lane * 2 + 1];
    float s = a.x*a.x + a.y*a.y + a.z*a.z + a.w*a.w
            + b.x*b.x + b.y*b.y + b.z*b.z + b.w*b.w;
    uint4 p;
    p.x = (unsigned)f2bf(a.x) | ((unsigned)f2bf(a.y) << 16);
    p.y = (unsigned)f2bf(a.z) | ((unsigned)f2bf(a.w) << 16);
    p.z = (unsigned)f2bf(b.x) | ((unsigned)f2bf(b.y) << 16);
    p.w = (unsigned)f2bf(b.z) | ((unsigned)f2bf(b.w) << 16);
    ((uint4*)(Xb + (size_t)row * DIM))[lane] = p;
    #pragma unroll
    for (int off = 32; off > 0; off >>= 1) s += __shfl_down(s, off);
    if (lane == 0) sq[row] = s;
  }

  // grid sync #1: all Xb/sq visible device-wide before any tile stages them
  __threadfence();                            // release own stores (wb L2)
  __syncthreads();
  if (tid == 0) {
    atomicAdd(&ctrl[4], 1u);
    while (atomicAdd(&ctrl[4], 0u) < NBLK) __builtin_amdgcn_s_sleep(8);
  }
  __syncthreads();
  __threadfence();                            // acquire (inv stale lines)

  // ---------------- phase 2: R3 tile loop (verbatim) --------------------------------------
  for (;;) {
    if (tid == 0) tshare = (int)atomicAdd(&ctrl[3], 1u);
    __syncthreads();
    int t = tshare;
    if (t >= NTILE) break;

    int It = 0, Js = 0, q = -1; bool strad = false;
    if (t < 64) { It = t; Js = t >> 1; strad = true; }
    else {
      int u;
      if (t < 1024) u = t - 64;                       // full above-diag: u in [0,960)
      else { q = (t - 1024) & 3; u = 960 + ((t - 1024) >> 2); }  // quarters: u in [960,992)
      for (int s = 0; s < 64; s++) {
        int c = 31 - (s >> 1);
        if (u < c) { It = s; Js = (s >> 1) + 1 + u; break; }
        u -= c;
      }
    }
    int i0 = It * 128;
    int jw = Js * 256 + (q >= 0 ? q * 64 : 0);

    f32x4 acc[4][8];
    #pragma unroll
    for (int mi = 0; mi < 4; mi++)
      #pragma unroll
      for (int ni = 0; ni < 8; ni++)
        acc[mi][ni] = (f32x4){0.f, 0.f, 0.f, 0.f};

    if (q >= 0) {
      gemm_tile<2>(Xb, i0, jw, Asm, Bsm, wave, wm, wn, quad, lc, rc, gcol, acc);
      epilogue<false, 2, 32>(acc, sq, labels, i0, jw, wm, wn, quad, lc, ibuf, jbuf);
    } else {
      gemm_tile<8>(Xb, i0, jw, Asm, Bsm, wave, wm, wn, quad, lc, rc, gcol, acc);
      if (strad)
        epilogue<true, 8, 128>(acc, sq, labels, i0, jw, wm, wn, quad, lc, ibuf, jbuf);
      else
        epilogue<false, 8, 128>(acc, sq, labels, i0, jw, wm, wn, quad, lc, ibuf, jbuf);
    }
    __syncthreads();

    // in-block combine + stores to slots
    if (q >= 0) {
      // quarter: 4 siblings share i-rows of slot (Js, i0..) -> atomic merge
      if (tid < 128) {
        unsigned p = max(ibuf[0][tid][0], ibuf[1][tid][0]);
        unsigned n = min(ibuf[0][tid][1], ibuf[1][tid][1]);
        atomicMax(&pos_i[(size_t)Js * BATCH + i0 + tid], p);
        atomicMin(&neg_i[(size_t)Js * BATCH + i0 + tid], n);
      }
      if (tid < 64) {   // j-cols disjoint across siblings -> plain stores
        unsigned p = max(jbuf[0][tid][0], jbuf[1][tid][0]);
        unsigned n = min(jbuf[0][tid][1], jbuf[1][tid][1]);
        pos_j[(size_t)It * BATCH + jw + tid] = p;
        neg_j[(size_t)It * BATCH + jw + tid] = n;
      }
    } else {
      if (tid < 128) {
        unsigned p = max(ibuf[0][tid][0], ibuf[1][tid][0]);
        unsigned n = min(ibuf[0][tid][1], ibuf[1][tid][1]);
        pos_i[(size_t)Js * BATCH + i0 + tid] = p;
        neg_i[(size_t)Js * BATCH + i0 + tid] = n;
      }
      if (!strad) {
        unsigned p = max(jbuf[0][tid][0], jbuf[1][tid][0]);
        unsigned n = min(jbuf[0][tid][1], jbuf[1][tid][1]);
        pos_j[(size_t)It * BATCH + jw + tid] = p;
        neg_j[(size_t)It * BATCH + jw + tid] = n;
      }
    }
    __syncthreads();   // protect overlay reads from next tile's staging writes
  }

  // grid sync #2: all slot stores visible before final reduction
  __threadfence();
  __syncthreads();
  if (tid == 0) {
    atomicAdd(&ctrl[5], 1u);
    while (atomicAdd(&ctrl[5], 0u) < NBLK) __builtin_amdgcn_s_sleep(8);
  }
  __syncthreads();
  __threadfence();

  // ---------------- phase 3: final reduction, 16 rows/block -------------------------------
  {
    int i = blockIdx.x * 16 + lc;              // 16 consecutive rows (coalesced)
    int g = wave * 4 + quad;                   // 0..15: slot group
    unsigned pe = 0u, ne = 0xFFFFFFFFu;
    #pragma unroll
    for (int s = 0; s < 32; s += 16) {
      pe = max(pe, pos_i[(size_t)(g + s) * BATCH + i]);
      ne = min(ne, neg_i[(size_t)(g + s) * BATCH + i]);
    }
    #pragma unroll
    for (int s = 0; s < 64; s += 16) {
      pe = max(pe, pos_j[(size_t)(g + s) * BATCH + i]);
      ne = min(ne, neg_j[(size_t)(g + s) * BATCH + i]);
    }
    // combine quads within wave (keeps lane&15)
    pe = max(pe, __shfl_xor(pe, 16)); ne = min(ne, __shfl_xor(ne, 16));
    pe = max(pe, __shfl_xor(pe, 32)); ne = min(ne, __shfl_xor(ne, 32));
    if (lane < 16) { fbuf[wave][lane][0] = pe; fbuf[wave][lane][1] = ne; }
    __syncthreads();
    if (wave == 0 && lane < 16) {
      pe = max(max(fbuf[0][lane][0], fbuf[1][lane][0]),
               max(fbuf[2][lane][0], fbuf[3][lane][0]));
      ne = min(min(fbuf[0][lane][1], fbuf[1][lane][1]),
               min(fbuf[2][lane][1], fbuf[3][lane][1]));
      float p = dec(pe), n = dec(ne);
      float term = 0.f, cnt = 0.f;
      if (p > -1e37f && n < 1e37f) {           // sentinel decodes fail => invalid row
        float si = sq[blockIdx.x * 16 + lane];
        float dp = sqrtf(fmaxf(si + p, 0.f) + 1e-16f);
        float dn = sqrtf(fmaxf(si + n, 0.f) + 1e-16f);
        term = fmaxf(dp - dn + 0.3f, 0.f);
        cnt = 1.f;
      }
      #pragma unroll
      for (int off = 8; off > 0; off >>= 1) {
        term += __shfl_down(term, off);
        cnt  += __shfl_down(cnt, off);
      }
      if (lane == 0) {
        atomicAdd((float*)&ctrl[0], term);
        atomicAdd((float*)&ctrl[1], cnt);
        __threadfence();
        unsigned tk = atomicAdd(&ctrl[2], 1u);
        if (tk == NBLK - 1) {
          float S = atomicAdd((float*)&ctrl[0], 0.f);
          float C = atomicAdd((float*)&ctrl[1], 0.f);
          out[0] = S / fmaxf(C, 1.f);
        }
      }
    }
  }
}

extern "C" void kernel_launch(void* const* d_in, const int* in_sizes, int n_in,
                              void* d_out, int out_size, void* d_ws, size_t ws_size,
                              hipStream_t stream) {
  const float* X      = (const float*)d_in[0];
  const int*   labels = (const int*)d_in[1];
  float* out = (float*)d_out;
  char* ws = (char*)d_ws;

  const size_t SLOT = (size_t)BATCH * 4;                 // 32 KB per slot
  unsigned short* Xb = (unsigned short*)ws;              // 8 MB
  float* sq      = (float*)(ws + (8u << 20));            // 32 KB
  unsigned* ctrl = (unsigned*)(ws + (8u << 20) + (32u << 10)); // sums|ticket|queue|syncs
  char*  posb = ws + (8u << 20) + (64u << 10);           // 96 slots = 3 MB
  char*  negb = posb + 96 * SLOT;                        // 96 slots = 3 MB
  unsigned* pos_i = (unsigned*)posb;                     // 32 slots keyed Js
  unsigned* pos_j = (unsigned*)(posb + 32 * SLOT);       // 64 slots keyed It
  unsigned* neg_i = (unsigned*)negb;
  unsigned* neg_j = (unsigned*)(negb + 32 * SLOT);

  hipMemsetAsync(ctrl, 0, 64, stream);                   // sums/ticket/queue/syncs = 0
  hipMemsetAsync(posb, 0x00, 96 * SLOT, stream);         // enc-min sentinel
  hipMemsetAsync(negb, 0xFF, 96 * SLOT, stream);         // enc-max sentinel
  triplet_fused<<<NBLK, 256, 0, stream>>>(X, labels, Xb, sq, ctrl,
                                          pos_i, neg_i, pos_j, neg_j, out);
}

// Round 7
// 178.956 us; speedup vs baseline: 2.0757x; 2.0757x over previous
//
#include <hip/hip_runtime.h>

#define BATCH 8192
#define DIM   512
// 64 straddle + 960 full above-diag + 128 quarter tiles (last 32 parents split 4-way in j)
#define NTILE 1152
#define NBLK  512
#define NRED  128          // last-128 finishers inline the final reduction

typedef __attribute__((ext_vector_type(4))) float  f32x4;
typedef __attribute__((ext_vector_type(8))) __bf16 bf16x8;

__device__ __forceinline__ unsigned short f2bf(float x) {
  unsigned u = __float_as_uint(x);
  u = (u + 0x7FFFu + ((u >> 16) & 1u)) >> 16;   // RNE
  return (unsigned short)u;
}

__device__ __forceinline__ void load_lds16(const void* g, void* l) {
  __builtin_amdgcn_global_load_lds(
      (__attribute__((address_space(1))) void*)(g),
      (__attribute__((address_space(3))) void*)(l), 16, 0, 0);
}

// monotone float <-> uint encoding (order-preserving); sentinels 0x00000000 / 0xFFFFFFFF
__device__ __forceinline__ unsigned enc(float f) {
  unsigned u = __float_as_uint(f);
  return u ^ (unsigned)(((int)u >> 31) | 0x80000000);
}
__device__ __forceinline__ float dec(unsigned k) {
  unsigned u = (k & 0x80000000u) ? (k ^ 0x80000000u) : ~k;
  return __uint_as_float(u);
}

// ---------------- prep: fp32->bf16, row norms, sentinel seeding, ctrl zeroing --------------
__global__ __launch_bounds__(256) void prep_kernel(
    const float* __restrict__ X, unsigned short* __restrict__ Xb,
    float* __restrict__ sq, unsigned* __restrict__ ctrl,
    uint4* __restrict__ pos4, uint4* __restrict__ neg4) {
  int gid = blockIdx.x * 256 + threadIdx.x;
  if (gid == 0) {
    ((float*)ctrl)[0] = 0.f;                   // sum of terms
    ((float*)ctrl)[1] = 0.f;                   // count
    ctrl[2] = 0u;                              // finish ticket (reducers)
    ctrl[3] = 0u;                              // tile queue head
    ctrl[4] = 0u;                              // completion-rank counter
    ctrl[5] = 0u;                              // (spare)
  }
  if (gid < 196608) {                          // 96 slots * 8192 * 4B / 16B
    pos4[gid] = (uint4){0u, 0u, 0u, 0u};       // enc-min sentinel (loses every max)
    neg4[gid] = (uint4){~0u, ~0u, ~0u, ~0u};   // enc-max sentinel (loses every min)
  }
  int wave = threadIdx.x >> 6, lane = threadIdx.x & 63;
  int row = blockIdx.x * 4 + wave;             // 2048 blocks * 4 waves = 8192 rows
  const float4* xr = (const float4*)(X + (size_t)row * DIM);
  float4 a = xr[lane * 2];
  float4 b = xr[lane * 2 + 1];
  float s = a.x*a.x + a.y*a.y + a.z*a.z + a.w*a.w
          + b.x*b.x + b.y*b.y + b.z*b.z + b.w*b.w;
  uint4 p;
  p.x = (unsigned)f2bf(a.x) | ((unsigned)f2bf(a.y) << 16);
  p.y = (unsigned)f2bf(a.z) | ((unsigned)f2bf(a.w) << 16);
  p.z = (unsigned)f2bf(b.x) | ((unsigned)f2bf(b.y) << 16);
  p.w = (unsigned)f2bf(b.z) | ((unsigned)f2bf(b.w) << 16);
  ((uint4*)(Xb + (size_t)row * DIM))[lane] = p;
  #pragma unroll
  for (int off = 32; off > 0; off >>= 1) s += __shfl_down(s, off);
  if (lane == 0) sq[row] = s;
}

// ---------------- K-loop for one 128 x (NI*32) tile (R3-verbatim) -----------------
// NI=8,WNS=128: full 128x256 tile.  NI=2,WNS=32: 128x64 quarter.
template<int NI>
__device__ __forceinline__ void gemm_tile(
    const unsigned short* __restrict__ Xb, int i0, int jw,
    unsigned short* Asm, unsigned short* Bsm,
    int wave, int wm, int wn, int quad, int lc, int rc, int gcol,
    f32x4 (&acc)[4][8]) {
  for (int k0 = 0; k0 < DIM; k0 += 64) {
    #pragma unroll
    for (int tt = 0; tt < 4; tt++) {
      int c = wave * 4 + tt;
      int row = c * 8 + rc;
      load_lds16(Xb + (size_t)(i0 + row) * DIM + k0 + gcol, &Asm[c * 512]);
    }
    #pragma unroll
    for (int tt = 0; tt < NI; tt++) {          // NI loads/thread covers NI*32 B-rows
      int c = wave * NI + tt;
      int row = c * 8 + rc;
      load_lds16(Xb + (size_t)(jw + row) * DIM + k0 + gcol, &Bsm[c * 512]);
    }
    __syncthreads();
    #pragma unroll
    for (int kk = 0; kk < 64; kk += 32) {
      int kc = kk >> 3;
      int asel = ((kc + quad) ^ (lc & 7)) * 8;
      bf16x8 af[4], bfr[NI];
      #pragma unroll
      for (int mi = 0; mi < 4; mi++)
        af[mi] = *(const bf16x8*)&Asm[(wm * 64 + mi * 16 + lc) * 64 + asel];
      #pragma unroll
      for (int ni = 0; ni < NI; ni++)
        bfr[ni] = *(const bf16x8*)&Bsm[(wn * (NI * 16) + ni * 16 + lc) * 64 + asel];
      #pragma unroll
      for (int mi = 0; mi < 4; mi++)
        #pragma unroll
        for (int ni = 0; ni < NI; ni++)
          acc[mi][ni] = __builtin_amdgcn_mfma_f32_16x16x32_bf16(
              af[mi], bfr[ni], acc[mi][ni], 0, 0, 0);
    }
    __syncthreads();
  }
}

// Epilogue: i-mining always; j-mining (transposed) unless STRAD (diag straddle).
template<bool STRAD, int NI, int WNS>
__device__ __forceinline__ void epilogue(
    const f32x4 (&acc)[4][8], const float* __restrict__ sq,
    const int* __restrict__ labels,
    int i0, int jwin, int wm, int wn, int quad, int lc,
    unsigned (*ibuf)[128][2], unsigned (*jbuf)[256][2]) {
  float sqj_r[NI]; int labj_r[NI];
  #pragma unroll
  for (int ni = 0; ni < NI; ni++) {
    int j = jwin + wn * WNS + ni * 16 + lc;
    sqj_r[ni] = sq[j]; labj_r[ni] = labels[j];
  }
  float rpos[16], rneg[16];
  float jp[NI], jn[NI];
  #pragma unroll
  for (int x = 0; x < NI; x++) { jp[x] = -3e38f; jn[x] = 3e38f; }
  #pragma unroll
  for (int mi = 0; mi < 4; mi++) {
    #pragma unroll
    for (int r = 0; r < 4; r++) {
      int ig = i0 + wm * 64 + mi * 16 + quad * 4 + r;
      int li = labels[ig];
      float si = sq[ig];
      float rp = -3e38f, rn = 3e38f;
      #pragma unroll
      for (int ni = 0; ni < NI; ni++) {
        float a = acc[mi][ni][r];
        float v = fmaf(-2.f, a, sqj_r[ni]);        // sq_j - 2dot (sq_i added at end)
        bool same = (li == labj_r[ni]);
        bool posok = same;
        if (STRAD) posok = same && ((jwin + wn * WNS + ni * 16 + lc) != ig);
        rp = fmaxf(rp, posok ? v : -3e38f);
        rn = fminf(rn, same ? 3e38f : v);
        if (!STRAD) {                              // j-mining: sq_i - 2dot per column
          float v2 = fmaf(-2.f, a, si);
          jp[ni] = fmaxf(jp[ni], same ? v2 : -3e38f);
          jn[ni] = fminf(jn[ni], same ? 3e38f : v2);
        }
      }
      rpos[mi * 4 + r] = rp; rneg[mi * 4 + r] = rn;
    }
  }
  #pragma unroll
  for (int m = 1; m <= 8; m <<= 1)
    #pragma unroll
    for (int x = 0; x < 16; x++) {
      rpos[x] = fmaxf(rpos[x], __shfl_xor(rpos[x], m));
      rneg[x] = fminf(rneg[x], __shfl_xor(rneg[x], m));
    }
  if (lc == 0) {
    #pragma unroll
    for (int mi = 0; mi < 4; mi++)
      #pragma unroll
      for (int r = 0; r < 4; r++) {
        int row = wm * 64 + mi * 16 + quad * 4 + r;
        ibuf[wn][row][0] = enc(rpos[mi * 4 + r]);
        ibuf[wn][row][1] = enc(rneg[mi * 4 + r]);
      }
  }
  if (!STRAD) {
    #pragma unroll
    for (int m = 16; m <= 32; m <<= 1)
      #pragma unroll
      for (int x = 0; x < NI; x++) {
        jp[x] = fmaxf(jp[x], __shfl_xor(jp[x], m));
        jn[x] = fminf(jn[x], __shfl_xor(jn[x], m));
      }
    if (quad == 0) {
      #pragma unroll
      for (int ni = 0; ni < NI; ni++) {
        int col = wn * WNS + ni * 16 + lc;
        jbuf[wm][col][0] = enc(jp[ni]);
        jbuf[wm][col][1] = enc(jn[ni]);
      }
    }
  }
}

// ---------------- main: R3 tile loop verbatim + completion-rank final tail ----------------
// R6 post-mortem: full grid syncs via atomic-RMW spin from 512 blocks serialize at the
// counter's home L2 bank (~100-200cyc/RMW) -> each "barrier" costs tens of us (320us
// kernel, MfmaUtil 4.3%). This round keeps R3's 3-kernel-era tile loop VERBATIM and
// takes only the cheap half of fusion: kill the final kernel. Each block fences its
// slot stores and takes a completion rank (ONE atomicAdd); ranks < 384 exit
// immediately (no spin, frees CU slots). The last 128 finishers (the 3rd-round
// quarter workers, which finish within a few us of each other) spin on a relaxed
// atomic LOAD (read-sharing, no RMW serialization; 1 thread/block + s_sleep) until
// rank==512, acquire-fence, then each reduces 64 rows with a 4-way slot split (4x
// the old final kernel's parallelism, L2-warm). Deadlock-free without co-residency
// assumptions: non-reducers exit unconditionally.
__global__ __launch_bounds__(256, 2) void triplet_mfma(
    const unsigned short* __restrict__ Xb, const float* __restrict__ sq,
    const int* __restrict__ labels, unsigned* __restrict__ ctrl,
    unsigned* __restrict__ pos_i, unsigned* __restrict__ neg_i,
    unsigned* __restrict__ pos_j, unsigned* __restrict__ neg_j,
    float* __restrict__ out) {
  __shared__ __align__(16) unsigned short Asm[128 * 64];  // 16 KB
  __shared__ __align__(16) unsigned short Bsm[256 * 64];  // 32 KB
  __shared__ int tshare;
  __shared__ unsigned sh_rank;

  // overlays on Asm (dead between K-loop end and next staging / after tile loop):
  unsigned (*ibuf)[128][2] = reinterpret_cast<unsigned (*)[128][2]>(&Asm[0]);
  unsigned (*jbuf)[256][2] = reinterpret_cast<unsigned (*)[256][2]>(&Asm[1024]);
  unsigned (*fbuf)[64][2]  = reinterpret_cast<unsigned (*)[64][2]>(&Asm[3072]); // 2 KB

  int tid = threadIdx.x;
  int wave = tid >> 6, lane = tid & 63;
  int wm = wave >> 1, wn = wave & 1;
  int quad = lane >> 4, lc = lane & 15;
  int rc = lane >> 3;
  int gcol = ((lane & 7) ^ rc) * 8;          // XOR swizzle (verified: 0 conflicts)

  for (;;) {
    if (tid == 0) tshare = (int)atomicAdd(&ctrl[3], 1u);
    __syncthreads();
    int t = tshare;
    if (t >= NTILE) break;

    int It = 0, Js = 0, q = -1; bool strad = false;
    if (t < 64) { It = t; Js = t >> 1; strad = true; }
    else {
      int u;
      if (t < 1024) u = t - 64;                       // full above-diag: u in [0,960)
      else { q = (t - 1024) & 3; u = 960 + ((t - 1024) >> 2); }  // quarters: u in [960,992)
      for (int s = 0; s < 64; s++) {
        int c = 31 - (s >> 1);
        if (u < c) { It = s; Js = (s >> 1) + 1 + u; break; }
        u -= c;
      }
    }
    int i0 = It * 128;
    int jw = Js * 256 + (q >= 0 ? q * 64 : 0);

    f32x4 acc[4][8];
    #pragma unroll
    for (int mi = 0; mi < 4; mi++)
      #pragma unroll
      for (int ni = 0; ni < 8; ni++)
        acc[mi][ni] = (f32x4){0.f, 0.f, 0.f, 0.f};

    if (q >= 0) {
      gemm_tile<2>(Xb, i0, jw, Asm, Bsm, wave, wm, wn, quad, lc, rc, gcol, acc);
      epilogue<false, 2, 32>(acc, sq, labels, i0, jw, wm, wn, quad, lc, ibuf, jbuf);
    } else {
      gemm_tile<8>(Xb, i0, jw, Asm, Bsm, wave, wm, wn, quad, lc, rc, gcol, acc);
      if (strad)
        epilogue<true, 8, 128>(acc, sq, labels, i0, jw, wm, wn, quad, lc, ibuf, jbuf);
      else
        epilogue<false, 8, 128>(acc, sq, labels, i0, jw, wm, wn, quad, lc, ibuf, jbuf);
    }
    __syncthreads();

    // in-block combine + stores to slots
    if (q >= 0) {
      // quarter: 4 siblings share i-rows of slot (Js, i0..) -> atomic merge
      if (tid < 128) {
        unsigned p = max(ibuf[0][tid][0], ibuf[1][tid][0]);
        unsigned n = min(ibuf[0][tid][1], ibuf[1][tid][1]);
        atomicMax(&pos_i[(size_t)Js * BATCH + i0 + tid], p);
        atomicMin(&neg_i[(size_t)Js * BATCH + i0 + tid], n);
      }
      if (tid < 64) {   // j-cols disjoint across siblings -> plain stores
        unsigned p = max(jbuf[0][tid][0], jbuf[1][tid][0]);
        unsigned n = min(jbuf[0][tid][1], jbuf[1][tid][1]);
        pos_j[(size_t)It * BATCH + jw + tid] = p;
        neg_j[(size_t)It * BATCH + jw + tid] = n;
      }
    } else {
      if (tid < 128) {
        unsigned p = max(ibuf[0][tid][0], ibuf[1][tid][0]);
        unsigned n = min(ibuf[0][tid][1], ibuf[1][tid][1]);
        pos_i[(size_t)Js * BATCH + i0 + tid] = p;
        neg_i[(size_t)Js * BATCH + i0 + tid] = n;
      }
      if (!strad) {
        unsigned p = max(jbuf[0][tid][0], jbuf[1][tid][0]);
        unsigned n = min(jbuf[0][tid][1], jbuf[1][tid][1]);
        pos_j[(size_t)It * BATCH + jw + tid] = p;
        neg_j[(size_t)It * BATCH + jw + tid] = n;
      }
    }
    __syncthreads();   // protect overlay reads from next tile's staging writes
  }

  // ---------------- completion-rank tail: last 128 finishers reduce ----------------
  __threadfence();                       // release each thread's slot stores
  __syncthreads();                       // all threads' fences precede the rank take
  if (tid == 0) sh_rank = atomicAdd(&ctrl[4], 1u);
  __syncthreads();
  unsigned rank = sh_rank;
  if (rank < NBLK - NRED) return;        // early finishers: exit, free the CU slot

  if (tid == 0) {                        // relaxed LOAD spin (no RMW serialization)
    unsigned v = __hip_atomic_load(&ctrl[4], __ATOMIC_RELAXED, __HIP_MEMORY_SCOPE_AGENT);
    while (v < NBLK) {
      __builtin_amdgcn_s_sleep(16);
      v = __hip_atomic_load(&ctrl[4], __ATOMIC_RELAXED, __HIP_MEMORY_SCOPE_AGENT);
    }
  }
  __syncthreads();
  __threadfence();                       // acquire: see all blocks' slot stores

  int part = (int)rank - (NBLK - NRED);  // 0..127
  int r = part * 64 + lane;              // this thread's row (lanes coalesced)
  int g = wave;                          // slot group 0..3 (24 slots each)
  unsigned pe = 0u, ne = 0xFFFFFFFFu;
  #pragma unroll
  for (int k = 0; k < 24; k++) {
    int s = g * 24 + k;                  // unified slot id: [0,32)=i-slots, [32,96)=j-slots
    const unsigned* ps = (s < 32) ? pos_i + (size_t)s * BATCH
                                  : pos_j + (size_t)(s - 32) * BATCH;
    const unsigned* ns = (s < 32) ? neg_i + (size_t)s * BATCH
                                  : neg_j + (size_t)(s - 32) * BATCH;
    pe = max(pe, ps[r]);
    ne = min(ne, ns[r]);
  }
  fbuf[wave][lane][0] = pe;
  fbuf[wave][lane][1] = ne;
  __syncthreads();
  if (wave == 0) {
    pe = max(max(fbuf[0][lane][0], fbuf[1][lane][0]),
             max(fbuf[2][lane][0], fbuf[3][lane][0]));
    ne = min(min(fbuf[0][lane][1], fbuf[1][lane][1]),
             min(fbuf[2][lane][1], fbuf[3][lane][1]));
    float p = dec(pe), n = dec(ne);
    float term = 0.f, cnt = 0.f;
    if (p > -1e37f && n < 1e37f) {       // sentinel decodes fail => invalid row
      float si = sq[part * 64 + lane];
      float dp = sqrtf(fmaxf(si + p, 0.f) + 1e-16f);
      float dn = sqrtf(fmaxf(si + n, 0.f) + 1e-16f);
      term = fmaxf(dp - dn + 0.3f, 0.f);
      cnt = 1.f;
    }
    #pragma unroll
    for (int off = 32; off > 0; off >>= 1) {
      term += __shfl_down(term, off);
      cnt  += __shfl_down(cnt, off);
    }
    if (lane == 0) {
      atomicAdd((float*)&ctrl[0], term);
      atomicAdd((float*)&ctrl[1], cnt);
      __threadfence();
      unsigned tk = atomicAdd(&ctrl[2], 1u);
      if (tk == NRED - 1) {
        float S = atomicAdd((float*)&ctrl[0], 0.f);
        float C = atomicAdd((float*)&ctrl[1], 0.f);
        out[0] = S / fmaxf(C, 1.f);
      }
    }
  }
}

extern "C" void kernel_launch(void* const* d_in, const int* in_sizes, int n_in,
                              void* d_out, int out_size, void* d_ws, size_t ws_size,
                              hipStream_t stream) {
  const float* X      = (const float*)d_in[0];
  const int*   labels = (const int*)d_in[1];
  float* out = (float*)d_out;
  char* ws = (char*)d_ws;

  const size_t SLOT = (size_t)BATCH * 4;                 // 32 KB per slot
  unsigned short* Xb = (unsigned short*)ws;              // 8 MB
  float* sq      = (float*)(ws + (8u << 20));            // 32 KB
  unsigned* ctrl = (unsigned*)(ws + (8u << 20) + (32u << 10)); // sums|ticket|queue|rank
  char*  posb = ws + (8u << 20) + (64u << 10);           // 96 slots = 3 MB
  char*  negb = posb + 96 * SLOT;                        // 96 slots = 3 MB
  unsigned* pos_i = (unsigned*)posb;                     // 32 slots keyed Js
  unsigned* pos_j = (unsigned*)(posb + 32 * SLOT);       // 64 slots keyed It
  unsigned* neg_i = (unsigned*)negb;
  unsigned* neg_j = (unsigned*)(negb + 32 * SLOT);

  prep_kernel<<<BATCH / 4, 256, 0, stream>>>(X, Xb, sq, ctrl,
                                             (uint4*)posb, (uint4*)negb);
  triplet_mfma<<<NBLK, 256, 0, stream>>>(Xb, sq, labels, ctrl,
                                         pos_i, neg_i, pos_j, neg_j, out);
}

// Round 8
// 141.562 us; speedup vs baseline: 2.6241x; 1.2642x over previous
//
#include <hip/hip_runtime.h>

#define BATCH 8192
#define DIM   512
// 64 straddle + 960 full above-diag + 128 quarter tiles (last 32 parents split 4-way in j)
#define NTILE 1152
#define NBLK  512
#define NRED  128          // last-128 finishers inline the final reduction

typedef __attribute__((ext_vector_type(4))) float  f32x4;
typedef __attribute__((ext_vector_type(8))) __bf16 bf16x8;

__device__ __forceinline__ unsigned short f2bf(float x) {
  unsigned u = __float_as_uint(x);
  u = (u + 0x7FFFu + ((u >> 16) & 1u)) >> 16;   // RNE
  return (unsigned short)u;
}

__device__ __forceinline__ void load_lds16(const void* g, void* l) {
  __builtin_amdgcn_global_load_lds(
      (__attribute__((address_space(1))) void*)(g),
      (__attribute__((address_space(3))) void*)(l), 16, 0, 0);
}

// monotone float <-> uint encoding (order-preserving); sentinels 0x00000000 / 0xFFFFFFFF
__device__ __forceinline__ unsigned enc(float f) {
  unsigned u = __float_as_uint(f);
  return u ^ (unsigned)(((int)u >> 31) | 0x80000000);
}
__device__ __forceinline__ float dec(unsigned k) {
  unsigned u = (k & 0x80000000u) ? (k ^ 0x80000000u) : ~k;
  return __uint_as_float(u);
}

// ---------------- prep: fp32->bf16, row norms, sentinel seeding, ctrl zeroing --------------
__global__ __launch_bounds__(256) void prep_kernel(
    const float* __restrict__ X, unsigned short* __restrict__ Xb,
    float* __restrict__ sq, unsigned* __restrict__ ctrl,
    uint4* __restrict__ pos4, uint4* __restrict__ neg4) {
  int gid = blockIdx.x * 256 + threadIdx.x;
  if (gid == 0) {
    ((float*)ctrl)[0] = 0.f;                   // sum of terms
    ((float*)ctrl)[1] = 0.f;                   // count
    ctrl[2] = 0u;                              // finish ticket (reducers)
    ctrl[3] = 0u;                              // tile queue head
    ctrl[4] = 0u;                              // completion-rank counter
    ctrl[5] = 0u;                              // (spare)
  }
  if (gid < 196608) {                          // 96 slots * 8192 * 4B / 16B
    pos4[gid] = (uint4){0u, 0u, 0u, 0u};       // enc-min sentinel (loses every max)
    neg4[gid] = (uint4){~0u, ~0u, ~0u, ~0u};   // enc-max sentinel (loses every min)
  }
  int wave = threadIdx.x >> 6, lane = threadIdx.x & 63;
  int row = blockIdx.x * 4 + wave;             // 2048 blocks * 4 waves = 8192 rows
  const float4* xr = (const float4*)(X + (size_t)row * DIM);
  float4 a = xr[lane * 2];
  float4 b = xr[lane * 2 + 1];
  float s = a.x*a.x + a.y*a.y + a.z*a.z + a.w*a.w
          + b.x*b.x + b.y*b.y + b.z*b.z + b.w*b.w;
  uint4 p;
  p.x = (unsigned)f2bf(a.x) | ((unsigned)f2bf(a.y) << 16);
  p.y = (unsigned)f2bf(a.z) | ((unsigned)f2bf(a.w) << 16);
  p.z = (unsigned)f2bf(b.x) | ((unsigned)f2bf(b.y) << 16);
  p.w = (unsigned)f2bf(b.z) | ((unsigned)f2bf(b.w) << 16);
  ((uint4*)(Xb + (size_t)row * DIM))[lane] = p;
  #pragma unroll
  for (int off = 32; off > 0; off >>= 1) s += __shfl_down(s, off);
  if (lane == 0) sq[row] = s;
}

// ---------------- K-loop for one 128 x (NI*32) tile (R3-verbatim) -----------------
// NI=8,WNS=128: full 128x256 tile.  NI=2,WNS=32: 128x64 quarter.
template<int NI>
__device__ __forceinline__ void gemm_tile(
    const unsigned short* __restrict__ Xb, int i0, int jw,
    unsigned short* Asm, unsigned short* Bsm,
    int wave, int wm, int wn, int quad, int lc, int rc, int gcol,
    f32x4 (&acc)[4][8]) {
  for (int k0 = 0; k0 < DIM; k0 += 64) {
    #pragma unroll
    for (int tt = 0; tt < 4; tt++) {
      int c = wave * 4 + tt;
      int row = c * 8 + rc;
      load_lds16(Xb + (size_t)(i0 + row) * DIM + k0 + gcol, &Asm[c * 512]);
    }
    #pragma unroll
    for (int tt = 0; tt < NI; tt++) {          // NI loads/thread covers NI*32 B-rows
      int c = wave * NI + tt;
      int row = c * 8 + rc;
      load_lds16(Xb + (size_t)(jw + row) * DIM + k0 + gcol, &Bsm[c * 512]);
    }
    __syncthreads();
    #pragma unroll
    for (int kk = 0; kk < 64; kk += 32) {
      int kc = kk >> 3;
      int asel = ((kc + quad) ^ (lc & 7)) * 8;
      bf16x8 af[4], bfr[NI];
      #pragma unroll
      for (int mi = 0; mi < 4; mi++)
        af[mi] = *(const bf16x8*)&Asm[(wm * 64 + mi * 16 + lc) * 64 + asel];
      #pragma unroll
      for (int ni = 0; ni < NI; ni++)
        bfr[ni] = *(const bf16x8*)&Bsm[(wn * (NI * 16) + ni * 16 + lc) * 64 + asel];
      #pragma unroll
      for (int mi = 0; mi < 4; mi++)
        #pragma unroll
        for (int ni = 0; ni < NI; ni++)
          acc[mi][ni] = __builtin_amdgcn_mfma_f32_16x16x32_bf16(
              af[mi], bfr[ni], acc[mi][ni], 0, 0, 0);
    }
    __syncthreads();
  }
}

// Epilogue: i-mining always; j-mining (transposed) unless STRAD (diag straddle).
template<bool STRAD, int NI, int WNS>
__device__ __forceinline__ void epilogue(
    const f32x4 (&acc)[4][8], const float* __restrict__ sq,
    const int* __restrict__ labels,
    int i0, int jwin, int wm, int wn, int quad, int lc,
    unsigned (*ibuf)[128][2], unsigned (*jbuf)[256][2]) {
  float sqj_r[NI]; int labj_r[NI];
  #pragma unroll
  for (int ni = 0; ni < NI; ni++) {
    int j = jwin + wn * WNS + ni * 16 + lc;
    sqj_r[ni] = sq[j]; labj_r[ni] = labels[j];
  }
  float rpos[16], rneg[16];
  float jp[NI], jn[NI];
  #pragma unroll
  for (int x = 0; x < NI; x++) { jp[x] = -3e38f; jn[x] = 3e38f; }
  #pragma unroll
  for (int mi = 0; mi < 4; mi++) {
    #pragma unroll
    for (int r = 0; r < 4; r++) {
      int ig = i0 + wm * 64 + mi * 16 + quad * 4 + r;
      int li = labels[ig];
      float si = sq[ig];
      float rp = -3e38f, rn = 3e38f;
      #pragma unroll
      for (int ni = 0; ni < NI; ni++) {
        float a = acc[mi][ni][r];
        float v = fmaf(-2.f, a, sqj_r[ni]);        // sq_j - 2dot (sq_i added at end)
        bool same = (li == labj_r[ni]);
        bool posok = same;
        if (STRAD) posok = same && ((jwin + wn * WNS + ni * 16 + lc) != ig);
        rp = fmaxf(rp, posok ? v : -3e38f);
        rn = fminf(rn, same ? 3e38f : v);
        if (!STRAD) {                              // j-mining: sq_i - 2dot per column
          float v2 = fmaf(-2.f, a, si);
          jp[ni] = fmaxf(jp[ni], same ? v2 : -3e38f);
          jn[ni] = fminf(jn[ni], same ? 3e38f : v2);
        }
      }
      rpos[mi * 4 + r] = rp; rneg[mi * 4 + r] = rn;
    }
  }
  #pragma unroll
  for (int m = 1; m <= 8; m <<= 1)
    #pragma unroll
    for (int x = 0; x < 16; x++) {
      rpos[x] = fmaxf(rpos[x], __shfl_xor(rpos[x], m));
      rneg[x] = fminf(rneg[x], __shfl_xor(rneg[x], m));
    }
  if (lc == 0) {
    #pragma unroll
    for (int mi = 0; mi < 4; mi++)
      #pragma unroll
      for (int r = 0; r < 4; r++) {
        int row = wm * 64 + mi * 16 + quad * 4 + r;
        ibuf[wn][row][0] = enc(rpos[mi * 4 + r]);
        ibuf[wn][row][1] = enc(rneg[mi * 4 + r]);
      }
  }
  if (!STRAD) {
    #pragma unroll
    for (int m = 16; m <= 32; m <<= 1)
      #pragma unroll
      for (int x = 0; x < NI; x++) {
        jp[x] = fmaxf(jp[x], __shfl_xor(jp[x], m));
        jn[x] = fminf(jn[x], __shfl_xor(jn[x], m));
      }
    if (quad == 0) {
      #pragma unroll
      for (int ni = 0; ni < NI; ni++) {
        int col = wn * WNS + ni * 16 + lc;
        jbuf[wm][col][0] = enc(jp[ni]);
        jbuf[wm][col][1] = enc(jn[ni]);
      }
    }
  }
}

// ---------------- main: R3 tile loop + fence-free completion-rank final tail ----------------
// R7 post-mortem: tile loop ran at full speed (MFMA busy time identical to R3) but the
// kernel idled ~55-60us in the spin — a RELAXED AGENT atomic LOAD was served from a
// stale local cached copy (remote RMWs update the coherence point but don't invalidate
// local copies); the spin only ended when a straggler's buffer_inv happened to flush it.
// Fix: make coherence fence-free BY CONSTRUCTION:
//   - ALL slot writes are device-scope atomicMax/Min (execute at the coherence point;
//     ~820K atomics to DISTINCT addresses over 62us = 13/us, no serialization — R6's
//     disaster was same-address unthrottled RMW spin, a different regime).
//   - rank taken after __syncthreads (implicit vmcnt(0) => block's atomics completed).
//   - spin polls with an RMW (atomicAdd(+0), definitionally coherent) every
//     s_sleep(127) (~3.4us): 128 pollers x 0.3/us each — bounded queueing, ~1000x
//     lighter than R6.
//   - reducers read slots via __hip_atomic_load(AGENT) (bypasses stale local cache).
// Early finishers (rank < 384) exit; last 128 reduce 64 rows each with a 4-way slot
// split. Deadlock-free: every block takes rank exactly once, unconditionally.
__global__ __launch_bounds__(256, 2) void triplet_mfma(
    const unsigned short* __restrict__ Xb, const float* __restrict__ sq,
    const int* __restrict__ labels, unsigned* __restrict__ ctrl,
    unsigned* __restrict__ pos_i, unsigned* __restrict__ neg_i,
    unsigned* __restrict__ pos_j, unsigned* __restrict__ neg_j,
    float* __restrict__ out) {
  __shared__ __align__(16) unsigned short Asm[128 * 64];  // 16 KB
  __shared__ __align__(16) unsigned short Bsm[256 * 64];  // 32 KB
  __shared__ int tshare;
  __shared__ unsigned sh_rank;

  // overlays on Asm (dead between K-loop end and next staging / after tile loop):
  unsigned (*ibuf)[128][2] = reinterpret_cast<unsigned (*)[128][2]>(&Asm[0]);
  unsigned (*jbuf)[256][2] = reinterpret_cast<unsigned (*)[256][2]>(&Asm[1024]);
  unsigned (*fbuf)[64][2]  = reinterpret_cast<unsigned (*)[64][2]>(&Asm[3072]); // 2 KB

  int tid = threadIdx.x;
  int wave = tid >> 6, lane = tid & 63;
  int wm = wave >> 1, wn = wave & 1;
  int quad = lane >> 4, lc = lane & 15;
  int rc = lane >> 3;
  int gcol = ((lane & 7) ^ rc) * 8;          // XOR swizzle (verified: 0 conflicts)

  for (;;) {
    if (tid == 0) tshare = (int)atomicAdd(&ctrl[3], 1u);
    __syncthreads();
    int t = tshare;
    if (t >= NTILE) break;

    int It = 0, Js = 0, q = -1; bool strad = false;
    if (t < 64) { It = t; Js = t >> 1; strad = true; }
    else {
      int u;
      if (t < 1024) u = t - 64;                       // full above-diag: u in [0,960)
      else { q = (t - 1024) & 3; u = 960 + ((t - 1024) >> 2); }  // quarters: u in [960,992)
      for (int s = 0; s < 64; s++) {
        int c = 31 - (s >> 1);
        if (u < c) { It = s; Js = (s >> 1) + 1 + u; break; }
        u -= c;
      }
    }
    int i0 = It * 128;
    int jw = Js * 256 + (q >= 0 ? q * 64 : 0);

    f32x4 acc[4][8];
    #pragma unroll
    for (int mi = 0; mi < 4; mi++)
      #pragma unroll
      for (int ni = 0; ni < 8; ni++)
        acc[mi][ni] = (f32x4){0.f, 0.f, 0.f, 0.f};

    if (q >= 0) {
      gemm_tile<2>(Xb, i0, jw, Asm, Bsm, wave, wm, wn, quad, lc, rc, gcol, acc);
      epilogue<false, 2, 32>(acc, sq, labels, i0, jw, wm, wn, quad, lc, ibuf, jbuf);
    } else {
      gemm_tile<8>(Xb, i0, jw, Asm, Bsm, wave, wm, wn, quad, lc, rc, gcol, acc);
      if (strad)
        epilogue<true, 8, 128>(acc, sq, labels, i0, jw, wm, wn, quad, lc, ibuf, jbuf);
      else
        epilogue<false, 8, 128>(acc, sq, labels, i0, jw, wm, wn, quad, lc, ibuf, jbuf);
    }
    __syncthreads();

    // in-block combine + device-scope atomic merge to slots (coherence point)
    if (tid < 128) {
      unsigned p = max(ibuf[0][tid][0], ibuf[1][tid][0]);
      unsigned n = min(ibuf[0][tid][1], ibuf[1][tid][1]);
      atomicMax(&pos_i[(size_t)Js * BATCH + i0 + tid], p);
      atomicMin(&neg_i[(size_t)Js * BATCH + i0 + tid], n);
    }
    if (q >= 0) {
      if (tid < 64) {
        unsigned p = max(jbuf[0][tid][0], jbuf[1][tid][0]);
        unsigned n = min(jbuf[0][tid][1], jbuf[1][tid][1]);
        atomicMax(&pos_j[(size_t)It * BATCH + jw + tid], p);
        atomicMin(&neg_j[(size_t)It * BATCH + jw + tid], n);
      }
    } else if (!strad) {
      unsigned p = max(jbuf[0][tid][0], jbuf[1][tid][0]);
      unsigned n = min(jbuf[0][tid][1], jbuf[1][tid][1]);
      atomicMax(&pos_j[(size_t)It * BATCH + jw + tid], p);
      atomicMin(&neg_j[(size_t)It * BATCH + jw + tid], n);
    }
    __syncthreads();   // protect overlay reads from next tile's staging writes
  }

  // ---------------- completion-rank tail: last 128 finishers reduce ----------------
  __syncthreads();                       // implicit vmcnt(0): slot atomics completed
  if (tid == 0) sh_rank = atomicAdd(&ctrl[4], 1u);
  __syncthreads();
  unsigned rank = sh_rank;
  if (rank < NBLK - NRED) return;        // early finishers: exit

  if (tid == 0) {
    unsigned v = __hip_atomic_load(&ctrl[4], __ATOMIC_ACQUIRE, __HIP_MEMORY_SCOPE_SYSTEM);
    while (v < NBLK) {
      __builtin_amdgcn_s_sleep(127);     // ~3.4 us
      v = atomicAdd(&ctrl[4], 0u);       // RMW poll: definitionally coherent
    }
  }
  __syncthreads();

  int part = (int)rank - (NBLK - NRED);  // 0..127
  int r = part * 64 + lane;              // this thread's row (lanes coalesced)
  int g = wave;                          // slot group 0..3 (24 slots each)
  unsigned pe = 0u, ne = 0xFFFFFFFFu;
  #pragma unroll
  for (int k = 0; k < 24; k++) {
    int s = g * 24 + k;                  // unified slot id: [0,32)=i-slots, [32,96)=j-slots
    const unsigned* ps = (s < 32) ? pos_i + (size_t)s * BATCH
                                  : pos_j + (size_t)(s - 32) * BATCH;
    const unsigned* ns = (s < 32) ? neg_i + (size_t)s * BATCH
                                  : neg_j + (size_t)(s - 32) * BATCH;
    pe = max(pe, __hip_atomic_load(ps + r, __ATOMIC_RELAXED, __HIP_MEMORY_SCOPE_AGENT));
    ne = min(ne, __hip_atomic_load(ns + r, __ATOMIC_RELAXED, __HIP_MEMORY_SCOPE_AGENT));
  }
  fbuf[wave][lane][0] = pe;
  fbuf[wave][lane][1] = ne;
  __syncthreads();
  if (wave == 0) {
    pe = max(max(fbuf[0][lane][0], fbuf[1][lane][0]),
             max(fbuf[2][lane][0], fbuf[3][lane][0]));
    ne = min(min(fbuf[0][lane][1], fbuf[1][lane][1]),
             min(fbuf[2][lane][1], fbuf[3][lane][1]));
    float p = dec(pe), n = dec(ne);
    float term = 0.f, cnt = 0.f;
    if (p > -1e37f && n < 1e37f) {       // sentinel decodes fail => invalid row
      float si = sq[part * 64 + lane];
      float dp = sqrtf(fmaxf(si + p, 0.f) + 1e-16f);
      float dn = sqrtf(fmaxf(si + n, 0.f) + 1e-16f);
      term = fmaxf(dp - dn + 0.3f, 0.f);
      cnt = 1.f;
    }
    #pragma unroll
    for (int off = 32; off > 0; off >>= 1) {
      term += __shfl_down(term, off);
      cnt  += __shfl_down(cnt, off);
    }
    if (lane == 0) {
      atomicAdd((float*)&ctrl[0], term);
      atomicAdd((float*)&ctrl[1], cnt);
      unsigned tk = atomicAdd(&ctrl[2], 1u);
      if (tk == NRED - 1) {
        float S = atomicAdd((float*)&ctrl[0], 0.f);
        float C = atomicAdd((float*)&ctrl[1], 0.f);
        out[0] = S / fmaxf(C, 1.f);
      }
    }
  }
}

extern "C" void kernel_launch(void* const* d_in, const int* in_sizes, int n_in,
                              void* d_out, int out_size, void* d_ws, size_t ws_size,
                              hipStream_t stream) {
  const float* X      = (const float*)d_in[0];
  const int*   labels = (const int*)d_in[1];
  float* out = (float*)d_out;
  char* ws = (char*)d_ws;

  const size_t SLOT = (size_t)BATCH * 4;                 // 32 KB per slot
  unsigned short* Xb = (unsigned short*)ws;              // 8 MB
  float* sq      = (float*)(ws + (8u << 20));            // 32 KB
  unsigned* ctrl = (unsigned*)(ws + (8u << 20) + (32u << 10)); // sums|ticket|queue|rank
  char*  posb = ws + (8u << 20) + (64u << 10);           // 96 slots = 3 MB
  char*  negb = posb + 96 * SLOT;                        // 96 slots = 3 MB
  unsigned* pos_i = (unsigned*)posb;                     // 32 slots keyed Js
  unsigned* pos_j = (unsigned*)(posb + 32 * SLOT);       // 64 slots keyed It
  unsigned* neg_i = (unsigned*)negb;
  unsigned* neg_j = (unsigned*)(negb + 32 * SLOT);

  prep_kernel<<<BATCH / 4, 256, 0, stream>>>(X, Xb, sq, ctrl,
                                             (uint4*)posb, (uint4*)negb);
  triplet_mfma<<<NBLK, 256, 0, stream>>>(Xb, sq, labels, ctrl,
                                         pos_i, neg_i, pos_j, neg_j, out);
}

// Round 9
// 133.286 us; speedup vs baseline: 2.7870x; 1.0621x over previous
//
#include <hip/hip_runtime.h>

#define BATCH 8192
#define DIM   512
// 64 straddle + 960 full above-diag + 128 quarter tiles (last 32 parents split 4-way in j)
#define NTILE 1152
#define NFIN  128          // final-kernel blocks

typedef __attribute__((ext_vector_type(4))) float  f32x4;
typedef __attribute__((ext_vector_type(8))) __bf16 bf16x8;

__device__ __forceinline__ unsigned short f2bf(float x) {
  unsigned u = __float_as_uint(x);
  u = (u + 0x7FFFu + ((u >> 16) & 1u)) >> 16;   // RNE
  return (unsigned short)u;
}

__device__ __forceinline__ void load_lds16(const void* g, void* l) {
  __builtin_amdgcn_global_load_lds(
      (__attribute__((address_space(1))) void*)(g),
      (__attribute__((address_space(3))) void*)(l), 16, 0, 0);
}

// monotone float <-> uint encoding (order-preserving); sentinels 0x00000000 / 0xFFFFFFFF
__device__ __forceinline__ unsigned enc(float f) {
  unsigned u = __float_as_uint(f);
  return u ^ (unsigned)(((int)u >> 31) | 0x80000000);
}
__device__ __forceinline__ float dec(unsigned k) {
  unsigned u = (k & 0x80000000u) ? (k ^ 0x80000000u) : ~k;
  return __uint_as_float(u);
}

// ---------------- prep: fp32->bf16, row norms, sentinel seeding, ctrl zeroing --------------
__global__ __launch_bounds__(256) void prep_kernel(
    const float* __restrict__ X, unsigned short* __restrict__ Xb,
    float* __restrict__ sq, unsigned* __restrict__ ctrl,
    uint4* __restrict__ pos4, uint4* __restrict__ neg4) {
  int gid = blockIdx.x * 256 + threadIdx.x;
  if (gid == 0) {
    ((float*)ctrl)[0] = 0.f;                   // sum of terms
    ((float*)ctrl)[1] = 0.f;                   // count
    ctrl[2] = 0u;                              // finish ticket
    ctrl[3] = 0u;                              // tile queue head
  }
  if (gid < 196608) {                          // 96 slots * 8192 * 4B / 16B
    pos4[gid] = (uint4){0u, 0u, 0u, 0u};       // enc-min sentinel (loses every max)
    neg4[gid] = (uint4){~0u, ~0u, ~0u, ~0u};   // enc-max sentinel (loses every min)
  }
  int wave = threadIdx.x >> 6, lane = threadIdx.x & 63;
  int row = blockIdx.x * 4 + wave;             // 2048 blocks * 4 waves = 8192 rows
  const float4* xr = (const float4*)(X + (size_t)row * DIM);
  float4 a = xr[lane * 2];
  float4 b = xr[lane * 2 + 1];
  float s = a.x*a.x + a.y*a.y + a.z*a.z + a.w*a.w
          + b.x*b.x + b.y*b.y + b.z*b.z + b.w*b.w;
  uint4 p;
  p.x = (unsigned)f2bf(a.x) | ((unsigned)f2bf(a.y) << 16);
  p.y = (unsigned)f2bf(a.z) | ((unsigned)f2bf(a.w) << 16);
  p.z = (unsigned)f2bf(b.x) | ((unsigned)f2bf(b.y) << 16);
  p.w = (unsigned)f2bf(b.z) | ((unsigned)f2bf(b.w) << 16);
  ((uint4*)(Xb + (size_t)row * DIM))[lane] = p;
  #pragma unroll
  for (int off = 32; off > 0; off >>= 1) s += __shfl_down(s, off);
  if (lane == 0) sq[row] = s;
}

// ---------------- full-tile K-loop (R3-verbatim): 128x256, BK=64 ------------------
__device__ __forceinline__ void gemm_full(
    const unsigned short* __restrict__ Xb, int i0, int jw,
    unsigned short* Asm, unsigned short* Bsm,
    int wave, int wm, int wn, int quad, int lc, int rc, int gcol,
    f32x4 (&acc)[4][8]) {
  for (int k0 = 0; k0 < DIM; k0 += 64) {
    #pragma unroll
    for (int tt = 0; tt < 4; tt++) {
      int c = wave * 4 + tt;
      int row = c * 8 + rc;
      load_lds16(Xb + (size_t)(i0 + row) * DIM + k0 + gcol, &Asm[c * 512]);
    }
    #pragma unroll
    for (int tt = 0; tt < 8; tt++) {
      int c = wave * 8 + tt;
      int row = c * 8 + rc;
      load_lds16(Xb + (size_t)(jw + row) * DIM + k0 + gcol, &Bsm[c * 512]);
    }
    __syncthreads();
    #pragma unroll
    for (int kk = 0; kk < 64; kk += 32) {
      int kc = kk >> 3;
      int asel = ((kc + quad) ^ (lc & 7)) * 8;
      bf16x8 af[4], bfr[8];
      #pragma unroll
      for (int mi = 0; mi < 4; mi++)
        af[mi] = *(const bf16x8*)&Asm[(wm * 64 + mi * 16 + lc) * 64 + asel];
      #pragma unroll
      for (int ni = 0; ni < 8; ni++)
        bfr[ni] = *(const bf16x8*)&Bsm[(wn * 128 + ni * 16 + lc) * 64 + asel];
      #pragma unroll
      for (int mi = 0; mi < 4; mi++)
        #pragma unroll
        for (int ni = 0; ni < 8; ni++)
          acc[mi][ni] = __builtin_amdgcn_mfma_f32_16x16x32_bf16(
              af[mi], bfr[ni], acc[mi][ni], 0, 0, 0);
    }
    __syncthreads();
  }
}

// ---------------- quarter-tile K-loop: 128x64, BK=128 (two 64-col panels/step) ----
// R3's tail calibration: T_step = F + M with F ~ 2.6M (fixed drain+barrier cost).
// Quarters at BK=64 pay 8 full F for M/4 => 0.79T. Staging TWO 64-col panels per
// barrier (4 steps total) halves the drain count while reusing the verified 64-col
// layout verbatim (panels = base offsets). A (128x128 = 32KB) lives in Bsm; B
// (64x128 = 16KB) lives in Asm. Instantaneous loads/thread/step = 12 (same as full).
__device__ __forceinline__ void gemm_quarter(
    const unsigned short* __restrict__ Xb, int i0, int jw,
    unsigned short* Asm, unsigned short* Bsm,
    int wave, int wm, int wn, int quad, int lc, int rc, int gcol,
    f32x4 (&acc)[4][8]) {
  unsigned short* QA = Bsm;                    // 2 panels x 8192 shorts
  unsigned short* QB = Asm;                    // 2 panels x 4096 shorts
  for (int k0 = 0; k0 < DIM; k0 += 128) {
    #pragma unroll
    for (int p = 0; p < 2; p++) {
      int kp = k0 + p * 64;
      #pragma unroll
      for (int tt = 0; tt < 4; tt++) {         // A: 128 rows
        int c = wave * 4 + tt;
        int row = c * 8 + rc;
        load_lds16(Xb + (size_t)(i0 + row) * DIM + kp + gcol, &QA[p * 8192 + c * 512]);
      }
      #pragma unroll
      for (int tt = 0; tt < 2; tt++) {         // B: 64 rows
        int c = wave * 2 + tt;
        int row = c * 8 + rc;
        load_lds16(Xb + (size_t)(jw + row) * DIM + kp + gcol, &QB[p * 4096 + c * 512]);
      }
    }
    __syncthreads();
    #pragma unroll
    for (int p = 0; p < 2; p++) {
      #pragma unroll
      for (int kk = 0; kk < 64; kk += 32) {
        int kc = kk >> 3;
        int asel = ((kc + quad) ^ (lc & 7)) * 8;
        bf16x8 af[4], bfr[2];
        #pragma unroll
        for (int mi = 0; mi < 4; mi++)
          af[mi] = *(const bf16x8*)&QA[p * 8192 + (wm * 64 + mi * 16 + lc) * 64 + asel];
        #pragma unroll
        for (int ni = 0; ni < 2; ni++)
          bfr[ni] = *(const bf16x8*)&QB[p * 4096 + (wn * 32 + ni * 16 + lc) * 64 + asel];
        #pragma unroll
        for (int mi = 0; mi < 4; mi++)
          #pragma unroll
          for (int ni = 0; ni < 2; ni++)
            acc[mi][ni] = __builtin_amdgcn_mfma_f32_16x16x32_bf16(
                af[mi], bfr[ni], acc[mi][ni], 0, 0, 0);
      }
    }
    __syncthreads();
  }
}

// Epilogue: i-mining always; j-mining (transposed) unless STRAD (diag straddle).
template<bool STRAD, int NI, int WNS>
__device__ __forceinline__ void epilogue(
    const f32x4 (&acc)[4][8], const float* __restrict__ sq,
    const int* __restrict__ labels,
    int i0, int jwin, int wm, int wn, int quad, int lc,
    unsigned (*ibuf)[128][2], unsigned (*jbuf)[256][2]) {
  float sqj_r[NI]; int labj_r[NI];
  #pragma unroll
  for (int ni = 0; ni < NI; ni++) {
    int j = jwin + wn * WNS + ni * 16 + lc;
    sqj_r[ni] = sq[j]; labj_r[ni] = labels[j];
  }
  float rpos[16], rneg[16];
  float jp[NI], jn[NI];
  #pragma unroll
  for (int x = 0; x < NI; x++) { jp[x] = -3e38f; jn[x] = 3e38f; }
  #pragma unroll
  for (int mi = 0; mi < 4; mi++) {
    #pragma unroll
    for (int r = 0; r < 4; r++) {
      int ig = i0 + wm * 64 + mi * 16 + quad * 4 + r;
      int li = labels[ig];
      float si = sq[ig];
      float rp = -3e38f, rn = 3e38f;
      #pragma unroll
      for (int ni = 0; ni < NI; ni++) {
        float a = acc[mi][ni][r];
        float v = fmaf(-2.f, a, sqj_r[ni]);        // sq_j - 2dot (sq_i added at end)
        bool same = (li == labj_r[ni]);
        bool posok = same;
        if (STRAD) posok = same && ((jwin + wn * WNS + ni * 16 + lc) != ig);
        rp = fmaxf(rp, posok ? v : -3e38f);
        rn = fminf(rn, same ? 3e38f : v);
        if (!STRAD) {                              // j-mining: sq_i - 2dot per column
          float v2 = fmaf(-2.f, a, si);
          jp[ni] = fmaxf(jp[ni], same ? v2 : -3e38f);
          jn[ni] = fminf(jn[ni], same ? 3e38f : v2);
        }
      }
      rpos[mi * 4 + r] = rp; rneg[mi * 4 + r] = rn;
    }
  }
  #pragma unroll
  for (int m = 1; m <= 8; m <<= 1)
    #pragma unroll
    for (int x = 0; x < 16; x++) {
      rpos[x] = fmaxf(rpos[x], __shfl_xor(rpos[x], m));
      rneg[x] = fminf(rneg[x], __shfl_xor(rneg[x], m));
    }
  if (lc == 0) {
    #pragma unroll
    for (int mi = 0; mi < 4; mi++)
      #pragma unroll
      for (int r = 0; r < 4; r++) {
        int row = wm * 64 + mi * 16 + quad * 4 + r;
        ibuf[wn][row][0] = enc(rpos[mi * 4 + r]);
        ibuf[wn][row][1] = enc(rneg[mi * 4 + r]);
      }
  }
  if (!STRAD) {
    #pragma unroll
    for (int m = 16; m <= 32; m <<= 1)
      #pragma unroll
      for (int x = 0; x < NI; x++) {
        jp[x] = fmaxf(jp[x], __shfl_xor(jp[x], m));
        jn[x] = fminf(jn[x], __shfl_xor(jn[x], m));
      }
    if (quad == 0) {
      #pragma unroll
      for (int ni = 0; ni < NI; ni++) {
        int col = wn * WNS + ni * 16 + lc;
        jbuf[wm][col][0] = enc(jp[ni]);
        jbuf[wm][col][1] = enc(jn[ni]);
      }
    }
  }
}

// ---------------- main: R3 verbatim except quarter K-loop at BK=128 ----------------
// R6-R8 post-mortem: non-kernel overhead is ~50-55us FIXED regardless of dispatch
// count (R3:57/3-launch, R8:55/2-launch, R6:51/1-launch+memsets) — fusion chased
// launch gaps that don't exist. Minimum e2e = overhead + sum(kernel times), so
// optimize the kernels: (1) quarter-tail at BK=128 (above), (2) final at 128 blocks.
__global__ __launch_bounds__(256, 2) void triplet_mfma(
    const unsigned short* __restrict__ Xb, const float* __restrict__ sq,
    const int* __restrict__ labels, unsigned* __restrict__ ctrl,
    unsigned* __restrict__ pos_i, unsigned* __restrict__ neg_i,
    unsigned* __restrict__ pos_j, unsigned* __restrict__ neg_j) {
  __shared__ __align__(16) unsigned short Asm[128 * 64];  // 16 KB
  __shared__ __align__(16) unsigned short Bsm[256 * 64];  // 32 KB
  __shared__ int tshare;

  // overlay: ibuf at Asm[0..1023] (2KB), jbuf at Asm[1024..3071] (4KB)
  unsigned (*ibuf)[128][2] = reinterpret_cast<unsigned (*)[128][2]>(&Asm[0]);
  unsigned (*jbuf)[256][2] = reinterpret_cast<unsigned (*)[256][2]>(&Asm[1024]);

  int tid = threadIdx.x;
  int wave = tid >> 6, lane = tid & 63;
  int wm = wave >> 1, wn = wave & 1;
  int quad = lane >> 4, lc = lane & 15;
  int rc = lane >> 3;
  int gcol = ((lane & 7) ^ rc) * 8;          // XOR swizzle (verified: 0 conflicts)

  for (;;) {
    if (tid == 0) tshare = (int)atomicAdd(&ctrl[3], 1u);
    __syncthreads();
    int t = tshare;
    if (t >= NTILE) break;

    int It = 0, Js = 0, q = -1; bool strad = false;
    if (t < 64) { It = t; Js = t >> 1; strad = true; }
    else {
      int u;
      if (t < 1024) u = t - 64;                       // full above-diag: u in [0,960)
      else { q = (t - 1024) & 3; u = 960 + ((t - 1024) >> 2); }  // quarters: u in [960,992)
      for (int s = 0; s < 64; s++) {
        int c = 31 - (s >> 1);
        if (u < c) { It = s; Js = (s >> 1) + 1 + u; break; }
        u -= c;
      }
    }
    int i0 = It * 128;
    int jw = Js * 256 + (q >= 0 ? q * 64 : 0);

    f32x4 acc[4][8];
    #pragma unroll
    for (int mi = 0; mi < 4; mi++)
      #pragma unroll
      for (int ni = 0; ni < 8; ni++)
        acc[mi][ni] = (f32x4){0.f, 0.f, 0.f, 0.f};

    if (q >= 0) {
      gemm_quarter(Xb, i0, jw, Asm, Bsm, wave, wm, wn, quad, lc, rc, gcol, acc);
      epilogue<false, 2, 32>(acc, sq, labels, i0, jw, wm, wn, quad, lc, ibuf, jbuf);
    } else {
      gemm_full(Xb, i0, jw, Asm, Bsm, wave, wm, wn, quad, lc, rc, gcol, acc);
      if (strad)
        epilogue<true, 8, 128>(acc, sq, labels, i0, jw, wm, wn, quad, lc, ibuf, jbuf);
      else
        epilogue<false, 8, 128>(acc, sq, labels, i0, jw, wm, wn, quad, lc, ibuf, jbuf);
    }
    __syncthreads();

    // in-block combine + stores to slots
    if (q >= 0) {
      // quarter: 4 siblings share i-rows of slot (Js, i0..) -> atomic merge
      if (tid < 128) {
        unsigned p = max(ibuf[0][tid][0], ibuf[1][tid][0]);
        unsigned n = min(ibuf[0][tid][1], ibuf[1][tid][1]);
        atomicMax(&pos_i[(size_t)Js * BATCH + i0 + tid], p);
        atomicMin(&neg_i[(size_t)Js * BATCH + i0 + tid], n);
      }
      if (tid < 64) {   // j-cols disjoint across siblings -> plain stores
        unsigned p = max(jbuf[0][tid][0], jbuf[1][tid][0]);
        unsigned n = min(jbuf[0][tid][1], jbuf[1][tid][1]);
        pos_j[(size_t)It * BATCH + jw + tid] = p;
        neg_j[(size_t)It * BATCH + jw + tid] = n;
      }
    } else {
      if (tid < 128) {
        unsigned p = max(ibuf[0][tid][0], ibuf[1][tid][0]);
        unsigned n = min(ibuf[0][tid][1], ibuf[1][tid][1]);
        pos_i[(size_t)Js * BATCH + i0 + tid] = p;
        neg_i[(size_t)Js * BATCH + i0 + tid] = n;
      }
      if (!strad) {
        unsigned p = max(jbuf[0][tid][0], jbuf[1][tid][0]);
        unsigned n = min(jbuf[0][tid][1], jbuf[1][tid][1]);
        pos_j[(size_t)It * BATCH + jw + tid] = p;
        neg_j[(size_t)It * BATCH + jw + tid] = n;
      }
    }
    __syncthreads();   // protect overlay reads from next tile's staging writes
  }
}

// ---------------- final v2: 128 blocks x 64 rows, 4-wave slot split ----------------
__global__ __launch_bounds__(256) void final_kernel(
    const unsigned* __restrict__ pos_i, const unsigned* __restrict__ neg_i,
    const unsigned* __restrict__ pos_j, const unsigned* __restrict__ neg_j,
    const float* __restrict__ sq, unsigned* __restrict__ ctrl,
    float* __restrict__ out) {
  __shared__ unsigned fbuf[4][64][2];
  int wave = threadIdx.x >> 6, lane = threadIdx.x & 63;
  int r = blockIdx.x * 64 + lane;           // rows coalesced across lanes
  unsigned pe = 0u, ne = 0xFFFFFFFFu;       // sentinels lose every comparison
  #pragma unroll
  for (int k = 0; k < 24; k++) {
    int s = wave * 24 + k;                  // slot id: [0,32)=i-slots, [32,96)=j-slots
    const unsigned* ps = (s < 32) ? pos_i + (size_t)s * BATCH
                                  : pos_j + (size_t)(s - 32) * BATCH;
    const unsigned* ns = (s < 32) ? neg_i + (size_t)s * BATCH
                                  : neg_j + (size_t)(s - 32) * BATCH;
    pe = max(pe, ps[r]);
    ne = min(ne, ns[r]);
  }
  fbuf[wave][lane][0] = pe;
  fbuf[wave][lane][1] = ne;
  __syncthreads();
  if (wave == 0) {
    pe = max(max(fbuf[0][lane][0], fbuf[1][lane][0]),
             max(fbuf[2][lane][0], fbuf[3][lane][0]));
    ne = min(min(fbuf[0][lane][1], fbuf[1][lane][1]),
             min(fbuf[2][lane][1], fbuf[3][lane][1]));
    float p = dec(pe), n = dec(ne);
    float term = 0.f, cnt = 0.f;
    if (p > -1e37f && n < 1e37f) {          // sentinel decodes fail => invalid row
      float si = sq[r];
      float dp = sqrtf(fmaxf(si + p, 0.f) + 1e-16f);
      float dn = sqrtf(fmaxf(si + n, 0.f) + 1e-16f);
      term = fmaxf(dp - dn + 0.3f, 0.f);
      cnt = 1.f;
    }
    #pragma unroll
    for (int off = 32; off > 0; off >>= 1) {
      term += __shfl_down(term, off);
      cnt  += __shfl_down(cnt, off);
    }
    if (lane == 0) {
      atomicAdd((float*)&ctrl[0], term);
      atomicAdd((float*)&ctrl[1], cnt);
      __threadfence();
      unsigned t = atomicAdd(&ctrl[2], 1u);
      if (t == NFIN - 1) {
        float S = atomicAdd((float*)&ctrl[0], 0.f);
        float C = atomicAdd((float*)&ctrl[1], 0.f);
        out[0] = S / fmaxf(C, 1.f);
      }
    }
  }
}

extern "C" void kernel_launch(void* const* d_in, const int* in_sizes, int n_in,
                              void* d_out, int out_size, void* d_ws, size_t ws_size,
                              hipStream_t stream) {
  const float* X      = (const float*)d_in[0];
  const int*   labels = (const int*)d_in[1];
  float* out = (float*)d_out;
  char* ws = (char*)d_ws;

  const size_t SLOT = (size_t)BATCH * 4;                 // 32 KB per slot
  unsigned short* Xb = (unsigned short*)ws;              // 8 MB
  float* sq      = (float*)(ws + (8u << 20));            // 32 KB
  unsigned* ctrl = (unsigned*)(ws + (8u << 20) + (32u << 10)); // sums|ticket|queue
  char*  posb = ws + (8u << 20) + (64u << 10);           // 96 slots = 3 MB
  char*  negb = posb + 96 * SLOT;                        // 96 slots = 3 MB
  unsigned* pos_i = (unsigned*)posb;                     // 32 slots keyed Js
  unsigned* pos_j = (unsigned*)(posb + 32 * SLOT);       // 64 slots keyed It
  unsigned* neg_i = (unsigned*)negb;
  unsigned* neg_j = (unsigned*)(negb + 32 * SLOT);

  prep_kernel<<<BATCH / 4, 256, 0, stream>>>(X, Xb, sq, ctrl,
                                             (uint4*)posb, (uint4*)negb);
  triplet_mfma<<<512, 256, 0, stream>>>(Xb, sq, labels, ctrl,
                                        pos_i, neg_i, pos_j, neg_j);
  final_kernel<<<NFIN, 256, 0, stream>>>(pos_i, neg_i, pos_j, neg_j, sq, ctrl, out);
}